// Round 8
// baseline (116.617 us; speedup 1.0000x reference)
//
#include <hip/hip_runtime.h>

#define NUM_LAYERS 32
#define HIDDEN 2048
#define RANK 64
#define BATCH 2048
#define CHK 256                // h-chunk (K for phase1, N for phase2)
#define SCP 4                  // sample-chunk grid split
#define MB 16                  // samples per block pass (one M=16 tile)
#define PPAD 72                // shorts/row pt (144 B = 9*16)

typedef __attribute__((ext_vector_type(8))) short bf16x8;
typedef __attribute__((ext_vector_type(4))) float f32x4;

static __device__ __forceinline__ ushort f2bf(float x) {
    unsigned b = __builtin_bit_cast(unsigned, x);
    b += 0x7fffu + ((b >> 16) & 1u);          // round-to-nearest-even
    return (ushort)(b >> 16);
}
static __device__ __forceinline__ ushort4 pack4(float4 v) {
    ushort4 r; r.x = f2bf(v.x); r.y = f2bf(v.y); r.z = f2bf(v.z); r.w = f2bf(v.w);
    return r;
}
static __device__ __forceinline__ bf16x8 cvt8(float4 a, float4 b) {
    bf16x8 r;
    r[0] = (short)f2bf(a.x); r[1] = (short)f2bf(a.y);
    r[2] = (short)f2bf(a.z); r[3] = (short)f2bf(a.w);
    r[4] = (short)f2bf(b.x); r[5] = (short)f2bf(b.y);
    r[6] = (short)f2bf(b.z); r[7] = (short)f2bf(b.w);
    return r;
}

// Workspace: proj[2048][64] f32 | counts[32] offsets[32] perm[2048]

// block 0: bucket sort; blocks 1..64: zero proj
__global__ __launch_bounds__(256)
void k_setup(const int* __restrict__ ids, float* __restrict__ proj,
             int* __restrict__ counts, int* __restrict__ offsets,
             int* __restrict__ perm)
{
    const int t = threadIdx.x;
    if (blockIdx.x == 0) {
        __shared__ int cnt[NUM_LAYERS];
        __shared__ int off[NUM_LAYERS];
        __shared__ int cur[NUM_LAYERS];
        if (t < NUM_LAYERS) cnt[t] = 0;
        __syncthreads();
        for (int i = t; i < BATCH; i += 256) atomicAdd(&cnt[ids[i]], 1);
        __syncthreads();
        if (t == 0) {
            int a = 0;
            for (int l = 0; l < NUM_LAYERS; ++l) { off[l] = a; a += cnt[l]; }
        }
        __syncthreads();
        if (t < NUM_LAYERS) { cur[t] = 0; counts[t] = cnt[t]; offsets[t] = off[t]; }
        __syncthreads();
        for (int i = t; i < BATCH; i += 256) {
            int l = ids[i];
            int p = off[l] + atomicAdd(&cur[l], 1);
            perm[p] = i;
        }
    } else {
        const int base = (blockIdx.x - 1) * (BATCH * RANK / 64);
        for (int i = t; i < BATCH * RANK / 64; i += 256) proj[base + i] = 0.0f;
    }
}

// K2: proj[b,r] += sum_{h in kc} z[b,h] * v[l,h,r]
// All operands direct from global with in-register fp32->bf16:
//   A[m=si=m16][k=quad*8+j] = z[bidx[m16]][...]   (8 contiguous fp32 / lane)
//   B[k=quad*8+j][n=r=w*16+m16] = v[h][r]         (8 strided fp32 / lane, L3-hot)
__global__ __launch_bounds__(256)
void k_proj(const float* __restrict__ z, const float* __restrict__ v,
            const int* __restrict__ counts, const int* __restrict__ offsets,
            const int* __restrict__ perm, float* __restrict__ proj)
{
    const int kc = blockIdx.x, l = blockIdx.y, sc = blockIdx.z;
    const int n = counts[l], o = offsets[l];
    if (sc * MB >= n) return;
    const int t = threadIdx.x;
    const int w = t >> 6, lane = t & 63;
    const int m16 = lane & 15, quad = lane >> 4;
    const int kbase = kc * CHK;

    __shared__ int bidx[MB];

    // per-lane V base: column r = w*16+m16, rows kbase+quad*8 ...
    const float* vp = v + ((size_t)l * HIDDEN + kbase + quad * 8) * RANK
                    + w * 16 + m16;

    for (int base = sc * MB; base < n; base += SCP * MB) {
        const int nb = (n - base < MB) ? (n - base) : MB;
        __syncthreads();
        if (t < MB) bidx[t] = (t < nb) ? perm[o + base + t] : 0;
        __syncthreads();

        const float* zp = z + (size_t)bidx[m16] * HIDDEN + kbase + quad * 8;

        f32x4 acc = {0.f, 0.f, 0.f, 0.f};
        #pragma unroll
        for (int kt = 0; kt < 8; ++kt) {
            const float4 a0 = *(const float4*)&zp[kt * 32];
            const float4 a1 = *(const float4*)&zp[kt * 32 + 4];
            float vj[8];
            #pragma unroll
            for (int j = 0; j < 8; ++j) vj[j] = vp[(size_t)(kt * 32 + j) * RANK];
            const bf16x8 a  = cvt8(a0, a1);
            const bf16x8 bm = cvt8(make_float4(vj[0], vj[1], vj[2], vj[3]),
                                   make_float4(vj[4], vj[5], vj[6], vj[7]));
            acc = __builtin_amdgcn_mfma_f32_16x16x32_bf16(a, bm, acc, 0, 0, 0);
        }
        // C/D: col = r-within-tile = m16, row = si = quad*4+reg
        #pragma unroll
        for (int reg = 0; reg < 4; ++reg) {
            const int row = quad * 4 + reg;
            if (row < nb)
                atomicAdd(&proj[(size_t)bidx[row] * RANK + w * 16 + m16], acc[reg]);
        }
    }
}

// K3: out[b,h] = z[b,h] + sum_r proj[b,r] * u[l,h,r]
//   A = P (staged fp32->bf16 via tiny LDS tile)
//   B[k=r][n=h] = u[h][r]  -> r-contiguous: direct fp32 dwordx4 + cvt
__global__ __launch_bounds__(256)
void k_delta(const float* __restrict__ z, const float* __restrict__ u,
             const int* __restrict__ counts, const int* __restrict__ offsets,
             const int* __restrict__ perm, const float* __restrict__ proj,
             float* __restrict__ out)
{
    const int hc = blockIdx.x, l = blockIdx.y, sc = blockIdx.z;
    const int n = counts[l], o = offsets[l];
    if (sc * MB >= n) return;
    const int t = threadIdx.x;
    const int w = t >> 6, lane = t & 63;
    const int m16 = lane & 15, quad = lane >> 4;
    const int hbase = hc * CHK;

    __shared__ ushort pt[MB * PPAD];   // 2.3 KB
    __shared__ int bidx[MB];

    const float* ub = u + ((size_t)l * HIDDEN + hbase) * RANK;

    for (int base = sc * MB; base < n; base += SCP * MB) {
        const int nb = (n - base < MB) ? (n - base) : MB;
        __syncthreads();
        if (t < MB) bidx[t] = (t < nb) ? perm[o + base + t] : 0;
        __syncthreads();
        // stage proj rows (fp32 -> bf16): 256 float4, 1 per thread
        {
            const int si = t >> 4, rq = t & 15;
            const float4 f = *(const float4*)&proj[(size_t)bidx[si] * RANK + rq * 4];
            *(ushort4*)&pt[si * PPAD + rq * 4] = pack4(f);
        }
        __syncthreads();

        // A-fragments of P (K=64): A[m=m16][k=quad*8+j]
        const bf16x8 pa0 = *(const bf16x8*)&pt[m16 * PPAD + quad * 8];
        const bf16x8 pa1 = *(const bf16x8*)&pt[m16 * PPAD + 32 + quad * 8];

        f32x4 acc[4];
        #pragma unroll
        for (int nt = 0; nt < 4; ++nt) acc[nt] = (f32x4){0.f, 0.f, 0.f, 0.f};
        #pragma unroll
        for (int nt = 0; nt < 4; ++nt) {
            const int hcol = (w * 4 + nt) * 16 + m16;
            const float* ur = ub + (size_t)hcol * RANK;
            const bf16x8 b0 = cvt8(*(const float4*)&ur[quad * 8],
                                   *(const float4*)&ur[quad * 8 + 4]);
            const bf16x8 b1 = cvt8(*(const float4*)&ur[32 + quad * 8],
                                   *(const float4*)&ur[32 + quad * 8 + 4]);
            acc[nt] = __builtin_amdgcn_mfma_f32_16x16x32_bf16(pa0, b0, acc[nt], 0, 0, 0);
            acc[nt] = __builtin_amdgcn_mfma_f32_16x16x32_bf16(pa1, b1, acc[nt], 0, 0, 0);
        }
        // epilogue: rows si=quad*4+reg, cols w*64 + nt*16 + m16
        #pragma unroll
        for (int reg = 0; reg < 4; ++reg) {
            const int si = quad * 4 + reg;
            if (si < nb) {
                const size_t rowb = (size_t)bidx[si] * HIDDEN + hbase;
                #pragma unroll
                for (int nt = 0; nt < 4; ++nt) {
                    const int hcol = (w * 4 + nt) * 16 + m16;
                    out[rowb + hcol] = z[rowb + hcol] + acc[nt][reg];
                }
            }
        }
    }
}

extern "C" void kernel_launch(void* const* d_in, const int* in_sizes, int n_in,
                              void* d_out, int out_size, void* d_ws, size_t ws_size,
                              hipStream_t stream)
{
    const float* z   = (const float*)d_in[0];
    const int*   ids = (const int*)d_in[1];
    const float* u   = (const float*)d_in[2];
    const float* v   = (const float*)d_in[3];
    float* out = (float*)d_out;

    float* proj  = (float*)d_ws;                       // 512 KB
    int* counts  = (int*)(proj + (size_t)BATCH * RANK);
    int* offsets = counts + NUM_LAYERS;
    int* perm    = offsets + NUM_LAYERS;

    hipLaunchKernelGGL(k_setup, dim3(65), dim3(256), 0, stream,
                       ids, proj, counts, offsets, perm);
    hipLaunchKernelGGL(k_proj, dim3(HIDDEN / CHK, NUM_LAYERS, SCP), dim3(256), 0, stream,
                       z, v, counts, offsets, perm, proj);
    hipLaunchKernelGGL(k_delta, dim3(HIDDEN / CHK, NUM_LAYERS, SCP), dim3(256), 0, stream,
                       z, u, counts, offsets, perm, proj, out);
}

// Round 9
// 115.444 us; speedup vs baseline: 1.0102x; 1.0102x over previous
//
#include <hip/hip_runtime.h>

#define NUM_LAYERS 32
#define HIDDEN 2048
#define RANK 64
#define BATCH 2048
#define CHK 256                // h-chunk (K for phase1, N for phase2)
#define SCP 2                  // sample-chunk grid split
#define MB 32                  // samples per block pass (two M=16 tiles)
#define PPAD 72                // shorts/row pt (144 B = 9*16)

typedef __attribute__((ext_vector_type(8))) short bf16x8;
typedef __attribute__((ext_vector_type(4))) float f32x4;

static __device__ __forceinline__ ushort f2bf(float x) {
    unsigned b = __builtin_bit_cast(unsigned, x);
    b += 0x7fffu + ((b >> 16) & 1u);          // round-to-nearest-even
    return (ushort)(b >> 16);
}
static __device__ __forceinline__ ushort4 pack4(float4 v) {
    ushort4 r; r.x = f2bf(v.x); r.y = f2bf(v.y); r.z = f2bf(v.z); r.w = f2bf(v.w);
    return r;
}
static __device__ __forceinline__ bf16x8 cvt8(float4 a, float4 b) {
    bf16x8 r;
    r[0] = (short)f2bf(a.x); r[1] = (short)f2bf(a.y);
    r[2] = (short)f2bf(a.z); r[3] = (short)f2bf(a.w);
    r[4] = (short)f2bf(b.x); r[5] = (short)f2bf(b.y);
    r[6] = (short)f2bf(b.z); r[7] = (short)f2bf(b.w);
    return r;
}

// Workspace: proj[2048][64] f32 | counts[32] offsets[32] perm[2048]

// block 0: bucket sort; blocks 1..64: zero proj
__global__ __launch_bounds__(256)
void k_setup(const int* __restrict__ ids, float* __restrict__ proj,
             int* __restrict__ counts, int* __restrict__ offsets,
             int* __restrict__ perm)
{
    const int t = threadIdx.x;
    if (blockIdx.x == 0) {
        __shared__ int cnt[NUM_LAYERS];
        __shared__ int off[NUM_LAYERS];
        __shared__ int cur[NUM_LAYERS];
        if (t < NUM_LAYERS) cnt[t] = 0;
        __syncthreads();
        for (int i = t; i < BATCH; i += 256) atomicAdd(&cnt[ids[i]], 1);
        __syncthreads();
        if (t == 0) {
            int a = 0;
            for (int l = 0; l < NUM_LAYERS; ++l) { off[l] = a; a += cnt[l]; }
        }
        __syncthreads();
        if (t < NUM_LAYERS) { cur[t] = 0; counts[t] = cnt[t]; offsets[t] = off[t]; }
        __syncthreads();
        for (int i = t; i < BATCH; i += 256) {
            int l = ids[i];
            int p = off[l] + atomicAdd(&cur[l], 1);
            perm[p] = i;
        }
    } else {
        const int base = (blockIdx.x - 1) * (BATCH * RANK / 64);
        for (int i = t; i < BATCH * RANK / 64; i += 256) proj[base + i] = 0.0f;
    }
}

// K2: proj[b,r] += sum_{h in kc} z[b,h] * v[l,h,r]
// Two M=16 tiles per pass share each B(V) fragment: v VMEM halved per sample.
//   A[m=si][k=quad*8+j] = z rows (contiguous fp32, cvt in-register)
//   B[k][n=r=w*16+m16]  = v[h][r] strided dwords (L2/L3-hot, loaded ONCE per kt)
__global__ __launch_bounds__(256)
void k_proj(const float* __restrict__ z, const float* __restrict__ v,
            const int* __restrict__ counts, const int* __restrict__ offsets,
            const int* __restrict__ perm, float* __restrict__ proj)
{
    const int kc = blockIdx.x, l = blockIdx.y, sc = blockIdx.z;
    const int n = counts[l], o = offsets[l];
    if (sc * MB >= n) return;
    const int t = threadIdx.x;
    const int w = t >> 6, lane = t & 63;
    const int m16 = lane & 15, quad = lane >> 4;
    const int kbase = kc * CHK;

    __shared__ int bidx[MB];

    // per-lane V base: column r = w*16+m16, rows kbase+quad*8 ...
    const float* vp = v + ((size_t)l * HIDDEN + kbase + quad * 8) * RANK
                    + w * 16 + m16;

    for (int base = sc * MB; base < n; base += SCP * MB) {
        const int nb = (n - base < MB) ? (n - base) : MB;
        __syncthreads();
        if (t < MB) bidx[t] = (t < nb) ? perm[o + base + t] : 0;
        __syncthreads();

        const float* zp0 = z + (size_t)bidx[m16] * HIDDEN + kbase + quad * 8;
        const float* zp1 = z + (size_t)bidx[16 + m16] * HIDDEN + kbase + quad * 8;

        f32x4 acc0 = {0.f, 0.f, 0.f, 0.f};
        f32x4 acc1 = {0.f, 0.f, 0.f, 0.f};
        #pragma unroll
        for (int kt = 0; kt < 8; ++kt) {
            float vj[8];
            #pragma unroll
            for (int j = 0; j < 8; ++j) vj[j] = vp[(size_t)(kt * 32 + j) * RANK];
            const bf16x8 bm = cvt8(make_float4(vj[0], vj[1], vj[2], vj[3]),
                                   make_float4(vj[4], vj[5], vj[6], vj[7]));
            const bf16x8 a0 = cvt8(*(const float4*)&zp0[kt * 32],
                                   *(const float4*)&zp0[kt * 32 + 4]);
            const bf16x8 a1 = cvt8(*(const float4*)&zp1[kt * 32],
                                   *(const float4*)&zp1[kt * 32 + 4]);
            acc0 = __builtin_amdgcn_mfma_f32_16x16x32_bf16(a0, bm, acc0, 0, 0, 0);
            acc1 = __builtin_amdgcn_mfma_f32_16x16x32_bf16(a1, bm, acc1, 0, 0, 0);
        }
        // C/D: col = r-within-tile = m16, row = si = quad*4+reg
        #pragma unroll
        for (int reg = 0; reg < 4; ++reg) {
            const int row = quad * 4 + reg;
            if (row < nb)
                atomicAdd(&proj[(size_t)bidx[row] * RANK + w * 16 + m16], acc0[reg]);
            if (16 + row < nb)
                atomicAdd(&proj[(size_t)bidx[16 + row] * RANK + w * 16 + m16], acc1[reg]);
        }
    }
}

// K3: out[b,h] = z[b,h] + sum_r proj[b,r] * u[l,h,r]
// Two M=16 tiles per pass share each B(U) fragment: u VMEM halved per sample.
//   A = P (staged fp32->bf16 via tiny LDS tile)
//   B[k=r][n=h] = u[h][r]  (r-contiguous: direct fp32 dwordx4 + cvt)
__global__ __launch_bounds__(256)
void k_delta(const float* __restrict__ z, const float* __restrict__ u,
             const int* __restrict__ counts, const int* __restrict__ offsets,
             const int* __restrict__ perm, const float* __restrict__ proj,
             float* __restrict__ out)
{
    const int hc = blockIdx.x, l = blockIdx.y, sc = blockIdx.z;
    const int n = counts[l], o = offsets[l];
    if (sc * MB >= n) return;
    const int t = threadIdx.x;
    const int w = t >> 6, lane = t & 63;
    const int m16 = lane & 15, quad = lane >> 4;
    const int hbase = hc * CHK;

    __shared__ ushort pt[MB * PPAD];   // 4.6 KB
    __shared__ int bidx[MB];

    const float* ub = u + ((size_t)l * HIDDEN + hbase) * RANK;

    for (int base = sc * MB; base < n; base += SCP * MB) {
        const int nb = (n - base < MB) ? (n - base) : MB;
        __syncthreads();
        if (t < MB) bidx[t] = (t < nb) ? perm[o + base + t] : 0;
        __syncthreads();
        // stage proj rows (fp32 -> bf16): 512 float4, 2 per thread
        #pragma unroll
        for (int it = 0; it < 2; ++it) {
            const int idx = it * 256 + t;
            const int si = idx >> 4, rq = idx & 15;
            const float4 f = *(const float4*)&proj[(size_t)bidx[si] * RANK + rq * 4];
            *(ushort4*)&pt[si * PPAD + rq * 4] = pack4(f);
        }
        __syncthreads();

        // A-fragments of P (K=64): A[m=m16][k=quad*8+j], two tiles
        const bf16x8 pa0 = *(const bf16x8*)&pt[m16 * PPAD + quad * 8];
        const bf16x8 pa1 = *(const bf16x8*)&pt[m16 * PPAD + 32 + quad * 8];
        const bf16x8 pb0 = *(const bf16x8*)&pt[(16 + m16) * PPAD + quad * 8];
        const bf16x8 pb1 = *(const bf16x8*)&pt[(16 + m16) * PPAD + 32 + quad * 8];

        f32x4 acc0[4], acc1[4];
        #pragma unroll
        for (int nt = 0; nt < 4; ++nt) {
            acc0[nt] = (f32x4){0.f, 0.f, 0.f, 0.f};
            acc1[nt] = (f32x4){0.f, 0.f, 0.f, 0.f};
        }
        #pragma unroll
        for (int nt = 0; nt < 4; ++nt) {
            const int hcol = (w * 4 + nt) * 16 + m16;
            const float* ur = ub + (size_t)hcol * RANK;
            const bf16x8 b0 = cvt8(*(const float4*)&ur[quad * 8],
                                   *(const float4*)&ur[quad * 8 + 4]);
            const bf16x8 b1 = cvt8(*(const float4*)&ur[32 + quad * 8],
                                   *(const float4*)&ur[32 + quad * 8 + 4]);
            acc0[nt] = __builtin_amdgcn_mfma_f32_16x16x32_bf16(pa0, b0, acc0[nt], 0, 0, 0);
            acc0[nt] = __builtin_amdgcn_mfma_f32_16x16x32_bf16(pa1, b1, acc0[nt], 0, 0, 0);
            acc1[nt] = __builtin_amdgcn_mfma_f32_16x16x32_bf16(pb0, b0, acc1[nt], 0, 0, 0);
            acc1[nt] = __builtin_amdgcn_mfma_f32_16x16x32_bf16(pb1, b1, acc1[nt], 0, 0, 0);
        }
        // epilogue: tile0 rows si=quad*4+reg, tile1 rows 16+..., cols w*64+nt*16+m16
        #pragma unroll
        for (int reg = 0; reg < 4; ++reg) {
            const int si = quad * 4 + reg;
            if (si < nb) {
                const size_t rowb = (size_t)bidx[si] * HIDDEN + hbase;
                #pragma unroll
                for (int nt = 0; nt < 4; ++nt) {
                    const int hcol = (w * 4 + nt) * 16 + m16;
                    out[rowb + hcol] = z[rowb + hcol] + acc0[nt][reg];
                }
            }
            if (16 + si < nb) {
                const size_t rowb = (size_t)bidx[16 + si] * HIDDEN + hbase;
                #pragma unroll
                for (int nt = 0; nt < 4; ++nt) {
                    const int hcol = (w * 4 + nt) * 16 + m16;
                    out[rowb + hcol] = z[rowb + hcol] + acc1[nt][reg];
                }
            }
        }
    }
}

extern "C" void kernel_launch(void* const* d_in, const int* in_sizes, int n_in,
                              void* d_out, int out_size, void* d_ws, size_t ws_size,
                              hipStream_t stream)
{
    const float* z   = (const float*)d_in[0];
    const int*   ids = (const int*)d_in[1];
    const float* u   = (const float*)d_in[2];
    const float* v   = (const float*)d_in[3];
    float* out = (float*)d_out;

    float* proj  = (float*)d_ws;                       // 512 KB
    int* counts  = (int*)(proj + (size_t)BATCH * RANK);
    int* offsets = counts + NUM_LAYERS;
    int* perm    = offsets + NUM_LAYERS;

    hipLaunchKernelGGL(k_setup, dim3(65), dim3(256), 0, stream,
                       ids, proj, counts, offsets, perm);
    hipLaunchKernelGGL(k_proj, dim3(HIDDEN / CHK, NUM_LAYERS, SCP), dim3(256), 0, stream,
                       z, v, counts, offsets, perm, proj);
    hipLaunchKernelGGL(k_delta, dim3(HIDDEN / CHK, NUM_LAYERS, SCP), dim3(256), 0, stream,
                       z, u, counts, offsets, perm, proj, out);
}

// Round 10
// 111.744 us; speedup vs baseline: 1.0436x; 1.0331x over previous
//
#include <hip/hip_runtime.h>

#define NUM_LAYERS 32
#define HIDDEN 2048
#define RANK 64
#define BATCH 2048
#define CHK 256                // h-chunk (K for phase1, N for phase2)
#define NKC (HIDDEN / CHK)     // 8 partial slices
#define SCP 2                  // sample-chunk grid split
#define MB 32                  // samples per block pass (two M=16 tiles)
#define VPAD 264               // shorts/row vt (528 B; stride 132 dw = 4 mod 32)
#define ZPAD 264               // shorts/row zt
#define UPAD 72                // shorts/row ut (144 B; stride 36 dw = 4 mod 32)
#define PPAD 72                // shorts/row pt

typedef __attribute__((ext_vector_type(8))) short bf16x8;
typedef __attribute__((ext_vector_type(4))) float f32x4;

static __device__ __forceinline__ ushort f2bf(float x) {
    unsigned b = __builtin_bit_cast(unsigned, x);
    b += 0x7fffu + ((b >> 16) & 1u);          // round-to-nearest-even
    return (ushort)(b >> 16);
}
static __device__ __forceinline__ ushort4 pack4(float4 v) {
    ushort4 r; r.x = f2bf(v.x); r.y = f2bf(v.y); r.z = f2bf(v.z); r.w = f2bf(v.w);
    return r;
}

// Workspace: partial[8][2048][64] f32 (4 MB, each element written exactly once)
//            | counts[32] offsets[32] perm[2048]

// single block: bucket sort only (no zeroing needed anymore)
__global__ __launch_bounds__(256)
void k_setup(const int* __restrict__ ids, int* __restrict__ counts,
             int* __restrict__ offsets, int* __restrict__ perm)
{
    const int t = threadIdx.x;
    __shared__ int cnt[NUM_LAYERS];
    __shared__ int off[NUM_LAYERS];
    __shared__ int cur[NUM_LAYERS];
    if (t < NUM_LAYERS) cnt[t] = 0;
    __syncthreads();
    for (int i = t; i < BATCH; i += 256) atomicAdd(&cnt[ids[i]], 1);
    __syncthreads();
    if (t == 0) {
        int a = 0;
        for (int l = 0; l < NUM_LAYERS; ++l) { off[l] = a; a += cnt[l]; }
    }
    __syncthreads();
    if (t < NUM_LAYERS) { cur[t] = 0; counts[t] = cnt[t]; offsets[t] = off[t]; }
    __syncthreads();
    for (int i = t; i < BATCH; i += 256) {
        int l = ids[i];
        int p = off[l] + atomicAdd(&cur[l], 1);
        perm[p] = i;
    }
}

// K2: partial[kc][b][r] = sum_{h in kc} z[b,h] * v[l,h,r]   (plain stores)
// vt: V-slice bf16 transposed in LDS (once per block); zt: 32 z rows bf16.
__global__ __launch_bounds__(256)
void k_proj(const float* __restrict__ z, const float* __restrict__ v,
            const int* __restrict__ counts, const int* __restrict__ offsets,
            const int* __restrict__ perm, float* __restrict__ partial)
{
    const int kc = blockIdx.x, l = blockIdx.y, sc = blockIdx.z;
    const int n = counts[l], o = offsets[l];
    if (sc * MB >= n) return;
    const int t = threadIdx.x;
    const int w = t >> 6, lane = t & 63;
    const int m16 = lane & 15, quad = lane >> 4;
    const int kbase = kc * CHK;

    __shared__ ushort vt[RANK * VPAD];   // 33 KB  [r][h]
    __shared__ ushort zt[MB * ZPAD];     // 16.5 KB [si][h]
    __shared__ int bidx[MB];

    // stage V slice transposed (fp32 coalesced reads -> bf16 LDS), once
    #pragma unroll
    for (int it = 0; it < 16; ++it) {
        const int idx = it * 256 + t;               // 4096 float4
        const int hh = idx >> 4, rq = idx & 15;
        const float4 f = *(const float4*)
            &v[((size_t)l * HIDDEN + kbase + hh) * RANK + rq * 4];
        vt[(rq * 4 + 0) * VPAD + hh] = f2bf(f.x);
        vt[(rq * 4 + 1) * VPAD + hh] = f2bf(f.y);
        vt[(rq * 4 + 2) * VPAD + hh] = f2bf(f.z);
        vt[(rq * 4 + 3) * VPAD + hh] = f2bf(f.w);
    }

    float* pout = partial + (size_t)kc * BATCH * RANK;

    for (int base = sc * MB; base < n; base += SCP * MB) {
        const int nb = (n - base < MB) ? (n - base) : MB;
        __syncthreads();              // vt ready (1st iter) / prior pass done
        if (t < MB) bidx[t] = (t < nb) ? perm[o + base + t] : perm[o + base];
        __syncthreads();
        // stage 32 z rows (fp32 -> bf16): 2048 float4, 8 per thread
        #pragma unroll
        for (int it = 0; it < 8; ++it) {
            const int idx = it * 256 + t;
            const int si = idx >> 6, q = idx & 63;
            const float4 f = *(const float4*)
                &z[(size_t)bidx[si] * HIDDEN + kbase + q * 4];
            *(ushort4*)&zt[si * ZPAD + q * 4] = pack4(f);
        }
        __syncthreads();

        f32x4 acc0 = {0.f, 0.f, 0.f, 0.f};
        f32x4 acc1 = {0.f, 0.f, 0.f, 0.f};
        #pragma unroll
        for (int kt = 0; kt < 8; ++kt) {
            const int koff = kt * 32 + quad * 8;
            const bf16x8 bm = *(const bf16x8*)&vt[(w * 16 + m16) * VPAD + koff];
            const bf16x8 a0 = *(const bf16x8*)&zt[m16 * ZPAD + koff];
            const bf16x8 a1 = *(const bf16x8*)&zt[(16 + m16) * ZPAD + koff];
            acc0 = __builtin_amdgcn_mfma_f32_16x16x32_bf16(a0, bm, acc0, 0, 0, 0);
            acc1 = __builtin_amdgcn_mfma_f32_16x16x32_bf16(a1, bm, acc1, 0, 0, 0);
        }
        // C/D: col=r-within-tile=m16, row=si=quad*4+reg -> plain stores
        #pragma unroll
        for (int reg = 0; reg < 4; ++reg) {
            const int row = quad * 4 + reg;
            if (row < nb)
                pout[(size_t)bidx[row] * RANK + w * 16 + m16] = acc0[reg];
            if (16 + row < nb)
                pout[(size_t)bidx[16 + row] * RANK + w * 16 + m16] = acc1[reg];
        }
    }
}

// K3: out[b,h] = z[b,h] + sum_r (sum_kc partial[kc][b][r]) * u[l,h,r]
// ut: U-slice bf16 in LDS (once); pt: proj rows summed from 8 partials.
__global__ __launch_bounds__(256)
void k_delta(const float* __restrict__ z, const float* __restrict__ u,
             const int* __restrict__ counts, const int* __restrict__ offsets,
             const int* __restrict__ perm, const float* __restrict__ partial,
             float* __restrict__ out)
{
    const int hc = blockIdx.x, l = blockIdx.y, sc = blockIdx.z;
    const int n = counts[l], o = offsets[l];
    if (sc * MB >= n) return;
    const int t = threadIdx.x;
    const int w = t >> 6, lane = t & 63;
    const int m16 = lane & 15, quad = lane >> 4;
    const int hbase = hc * CHK;

    __shared__ ushort ut[CHK * UPAD];    // 36.9 KB [h][r]
    __shared__ ushort pt[MB * PPAD];     // 4.6 KB  [si][r]
    __shared__ int bidx[MB];

    // stage U slice (fp32 coalesced -> bf16 LDS, natural layout), once
    #pragma unroll
    for (int it = 0; it < 16; ++it) {
        const int idx = it * 256 + t;               // 4096 float4
        const int hh = idx >> 4, rq = idx & 15;
        const float4 f = *(const float4*)
            &u[((size_t)l * HIDDEN + hbase + hh) * RANK + rq * 4];
        *(ushort4*)&ut[hh * UPAD + rq * 4] = pack4(f);
    }

    for (int base = sc * MB; base < n; base += SCP * MB) {
        const int nb = (n - base < MB) ? (n - base) : MB;
        __syncthreads();              // ut ready (1st iter) / prior pass done
        if (t < MB) bidx[t] = (t < nb) ? perm[o + base + t] : perm[o + base];
        __syncthreads();
        // stage proj rows: sum 8 kc-partials, fp32 -> bf16 (2 float4/thread)
        #pragma unroll
        for (int it = 0; it < 2; ++it) {
            const int idx = it * 256 + t;
            const int si = idx >> 4, rq = idx & 15;
            const float* pk = partial + (size_t)bidx[si] * RANK + rq * 4;
            float4 s = *(const float4*)pk;
            #pragma unroll
            for (int kc = 1; kc < NKC; ++kc) {
                const float4 p = *(const float4*)&pk[(size_t)kc * BATCH * RANK];
                s.x += p.x; s.y += p.y; s.z += p.z; s.w += p.w;
            }
            *(ushort4*)&pt[si * PPAD + rq * 4] = pack4(s);
        }
        __syncthreads();

        // A-fragments of P (K=64): A[m][k=quad*8+j], two M-tiles
        const bf16x8 pa0 = *(const bf16x8*)&pt[m16 * PPAD + quad * 8];
        const bf16x8 pa1 = *(const bf16x8*)&pt[m16 * PPAD + 32 + quad * 8];
        const bf16x8 pb0 = *(const bf16x8*)&pt[(16 + m16) * PPAD + quad * 8];
        const bf16x8 pb1 = *(const bf16x8*)&pt[(16 + m16) * PPAD + 32 + quad * 8];

        f32x4 acc0[4], acc1[4];
        #pragma unroll
        for (int nt = 0; nt < 4; ++nt) {
            acc0[nt] = (f32x4){0.f, 0.f, 0.f, 0.f};
            acc1[nt] = (f32x4){0.f, 0.f, 0.f, 0.f};
        }
        #pragma unroll
        for (int nt = 0; nt < 4; ++nt) {
            const int hcol = (w * 4 + nt) * 16 + m16;
            const bf16x8 b0 = *(const bf16x8*)&ut[hcol * UPAD + quad * 8];
            const bf16x8 b1 = *(const bf16x8*)&ut[hcol * UPAD + 32 + quad * 8];
            acc0[nt] = __builtin_amdgcn_mfma_f32_16x16x32_bf16(pa0, b0, acc0[nt], 0, 0, 0);
            acc0[nt] = __builtin_amdgcn_mfma_f32_16x16x32_bf16(pa1, b1, acc0[nt], 0, 0, 0);
            acc1[nt] = __builtin_amdgcn_mfma_f32_16x16x32_bf16(pb0, b0, acc1[nt], 0, 0, 0);
            acc1[nt] = __builtin_amdgcn_mfma_f32_16x16x32_bf16(pb1, b1, acc1[nt], 0, 0, 0);
        }
        // epilogue
        #pragma unroll
        for (int reg = 0; reg < 4; ++reg) {
            const int si = quad * 4 + reg;
            if (si < nb) {
                const size_t rowb = (size_t)bidx[si] * HIDDEN + hbase;
                #pragma unroll
                for (int nt = 0; nt < 4; ++nt) {
                    const int hcol = (w * 4 + nt) * 16 + m16;
                    out[rowb + hcol] = z[rowb + hcol] + acc0[nt][reg];
                }
            }
            if (16 + si < nb) {
                const size_t rowb = (size_t)bidx[16 + si] * HIDDEN + hbase;
                #pragma unroll
                for (int nt = 0; nt < 4; ++nt) {
                    const int hcol = (w * 4 + nt) * 16 + m16;
                    out[rowb + hcol] = z[rowb + hcol] + acc1[nt][reg];
                }
            }
        }
    }
}

extern "C" void kernel_launch(void* const* d_in, const int* in_sizes, int n_in,
                              void* d_out, int out_size, void* d_ws, size_t ws_size,
                              hipStream_t stream)
{
    const float* z   = (const float*)d_in[0];
    const int*   ids = (const int*)d_in[1];
    const float* u   = (const float*)d_in[2];
    const float* v   = (const float*)d_in[3];
    float* out = (float*)d_out;

    float* partial = (float*)d_ws;                              // 4 MB
    int* counts  = (int*)(partial + (size_t)NKC * BATCH * RANK);
    int* offsets = counts + NUM_LAYERS;
    int* perm    = offsets + NUM_LAYERS;

    hipLaunchKernelGGL(k_setup, dim3(1), dim3(256), 0, stream,
                       ids, counts, offsets, perm);
    hipLaunchKernelGGL(k_proj, dim3(NKC, NUM_LAYERS, SCP), dim3(256), 0, stream,
                       z, v, counts, offsets, perm, partial);
    hipLaunchKernelGGL(k_delta, dim3(HIDDEN / CHK, NUM_LAYERS, SCP), dim3(256), 0, stream,
                       z, u, counts, offsets, perm, partial, out);
}